// Round 1
// 4134.809 us; speedup vs baseline: 2.7234x; 2.7234x over previous
//
#include <hip/hip_runtime.h>
#include <math.h>

#define DD 512
#define SS 1024
#define BB 2
#define HH 8
#define LL 8
#define FF 2048
#define VV 32000
#define ROWS 2048            // B*S
#define NTOT 65536000u       // B*S*V
#define NCHUNK 16
#define CLEN 64              // SS / NCHUNK

// ---------------------------------------------------------------- embedding
__global__ __launch_bounds__(256) void embed_kernel(
    const int* __restrict__ ids, const float* __restrict__ emb,
    const float* __restrict__ pos, float* __restrict__ x)
{
    unsigned idx = blockIdx.x * 256u + threadIdx.x;        // ROWS*DD
    unsigned row = idx >> 9, d = idx & 511u;
    unsigned s = row & (SS - 1);
    x[idx] = emb[(size_t)ids[row] * DD + d] + pos[(size_t)s * DD + d];
}

// ---------------------------------------------------------------- rope tables
__global__ __launch_bounds__(256) void rope_table_kernel(float* __restrict__ ctab,
                                                         float* __restrict__ stab)
{
    unsigned idx = blockIdx.x * 256u + threadIdx.x;        // SS*32
    unsigned j = idx & 31u, s = idx >> 5;
    float invf = (float)(1.0 / pow(10000.0, (double)(2 * j) / 64.0));
    float f = (float)s * invf;                              // fp32 mult, like np
    ctab[idx] = (float)cos((double)f);
    stab[idx] = (float)sin((double)f);
}

// ---------------------------------------------------------------- rope + elu+1
__device__ __forceinline__ float elu1(float x) {
    return x > 0.f ? x + 1.f : expm1f(x) + 1.f;
}

__global__ __launch_bounds__(256) void rope_feat_kernel(
    float* __restrict__ q, float* __restrict__ k,
    const float* __restrict__ ctab, const float* __restrict__ stab,
    const float* __restrict__ mask)
{
    unsigned idx = blockIdx.x * 256u + threadIdx.x;        // ROWS*HH*32
    unsigned j = idx & 31u;
    unsigned h = (idx >> 5) & 7u;
    unsigned row = idx >> 8;
    unsigned s = row & (SS - 1);
    float c = ctab[s * 32 + j], sn = stab[s * 32 + j];
    size_t o = (size_t)row * DD + h * 64 + j;
    float q1 = q[o], q2 = q[o + 32];
    float qa = q1 * c - q2 * sn;   // d<32: rot = -q[d+32]
    float qb = q2 * c + q1 * sn;   // d>=32: rot = q[d-32]
    q[o]      = elu1(qa);
    q[o + 32] = elu1(qb);
    float m = mask[row];
    float k1 = k[o], k2 = k[o + 32];
    float ka = k1 * c - k2 * sn;
    float kb = k2 * c + k1 * sn;
    k[o]      = elu1(ka) * m;
    k[o + 32] = elu1(kb) * m;
}

// ---------------------------------------------------------------- chunked linear attention
// Stage A: per-(b,h,chunk) partial state  S_c[d][e] = sum_{s in c} k[s][d]*v[s][e]
//          and z_c[d] = sum_{s in c} k[s][d].   grid = B*H*NCHUNK = 256 blocks.
__global__ __launch_bounds__(256) void chunk_state_kernel(
    const float* __restrict__ k, const float* __restrict__ v,
    float* __restrict__ st, float* __restrict__ zs)
{
    int blk = blockIdx.x;                 // bh*16 + c
    int bh = blk >> 4, c = blk & 15;
    int b = bh >> 3, h = bh & 7;
    int t = threadIdx.x;
    int e = t & 63, dg = t >> 6, d0 = dg << 4;
    size_t base = (size_t)b * SS * DD + (size_t)h * 64 + (size_t)(c * CLEN) * DD;
    __shared__ float kk[64][64], vv[64][64];
#pragma unroll
    for (int i = 0; i < 4; ++i) {
        int idx = t + i * 256;
        int r = idx >> 4, c4 = (idx & 15) << 2;
        size_t go = base + (size_t)r * DD + c4;
        *(float4*)&kk[r][c4] = *(const float4*)(k + go);
        *(float4*)&vv[r][c4] = *(const float4*)(v + go);
    }
    __syncthreads();
    float acc[16];
#pragma unroll
    for (int j = 0; j < 16; ++j) acc[j] = 0.f;
    float z = 0.f;
    for (int s = 0; s < CLEN; ++s) {
        float vval = vv[s][e];
        float kr16[16];
        *(float4*)&kr16[0]  = *(const float4*)&kk[s][d0];
        *(float4*)&kr16[4]  = *(const float4*)&kk[s][d0 + 4];
        *(float4*)&kr16[8]  = *(const float4*)&kk[s][d0 + 8];
        *(float4*)&kr16[12] = *(const float4*)&kk[s][d0 + 12];
#pragma unroll
        for (int j = 0; j < 16; ++j) acc[j] += kr16[j] * vval;
        if (t < 64) z += kk[s][t];
    }
    size_t so = (size_t)blk * 4096;
#pragma unroll
    for (int j = 0; j < 16; ++j)
        st[so + (size_t)(d0 + j) * 64 + e] = acc[j];
    if (t < 64) zs[(size_t)blk * 64 + t] = z;
}

// Stage B: in-place EXCLUSIVE prefix over the 16 chunks per (b,h). grid = 16.
__global__ __launch_bounds__(256) void chunk_prefix_kernel(
    float* __restrict__ st, float* __restrict__ zs)
{
    int bh = blockIdx.x;
    int t = threadIdx.x;
    float run[16];
#pragma unroll
    for (int i = 0; i < 16; ++i) run[i] = 0.f;
    float zrun = 0.f;
    for (int c = 0; c < NCHUNK; ++c) {
        size_t so = ((size_t)bh * NCHUNK + c) * 4096;
#pragma unroll
        for (int i = 0; i < 16; ++i) {
            size_t o = so + t + i * 256;
            float tmp = st[o];
            st[o] = run[i];
            run[i] += tmp;
        }
        if (t < 64) {
            size_t zo = ((size_t)bh * NCHUNK + c) * 64 + t;
            float tz = zs[zo];
            zs[zo] = zrun;
            zrun += tz;
        }
    }
}

// Stage C: per-chunk 64-step scan seeded from the exclusive prefix state.
// Same arithmetic order as the original serial scan within a chunk.
// grid = 256 blocks; q/k/v chunk staged in LDS so the loop has no global latency.
__global__ __launch_bounds__(256) void chunk_scan_kernel(
    const float* __restrict__ q, const float* __restrict__ k,
    const float* __restrict__ v, float* __restrict__ a,
    const float* __restrict__ st, const float* __restrict__ zs)
{
    int blk = blockIdx.x;
    int bh = blk >> 4, c = blk & 15;
    int b = bh >> 3, h = bh & 7;
    int t = threadIdx.x;
    int e = t & 63, dg = t >> 6, d0 = dg << 4;
    size_t base = (size_t)b * SS * DD + (size_t)h * 64 + (size_t)(c * CLEN) * DD;
    __shared__ float kk[64][64], vv[64][64], qq[64][64];
    __shared__ float pnum[4][64];
    __shared__ float den_sh;
#pragma unroll
    for (int i = 0; i < 4; ++i) {
        int idx = t + i * 256;
        int r = idx >> 4, c4 = (idx & 15) << 2;
        size_t go = base + (size_t)r * DD + c4;
        *(float4*)&kk[r][c4] = *(const float4*)(k + go);
        *(float4*)&vv[r][c4] = *(const float4*)(v + go);
        *(float4*)&qq[r][c4] = *(const float4*)(q + go);
    }
    float Sacc[16];
    size_t so = (size_t)blk * 4096;
#pragma unroll
    for (int j = 0; j < 16; ++j)
        Sacc[j] = st[so + (size_t)(d0 + j) * 64 + e];
    float zreg = 0.f;
    if (t < 64) zreg = zs[(size_t)blk * 64 + t];
    __syncthreads();
    for (int s = 0; s < CLEN; ++s) {
        float vval = vv[s][e];
        float kr16[16], qr16[16];
        *(float4*)&kr16[0]  = *(const float4*)&kk[s][d0];
        *(float4*)&kr16[4]  = *(const float4*)&kk[s][d0 + 4];
        *(float4*)&kr16[8]  = *(const float4*)&kk[s][d0 + 8];
        *(float4*)&kr16[12] = *(const float4*)&kk[s][d0 + 12];
        *(float4*)&qr16[0]  = *(const float4*)&qq[s][d0];
        *(float4*)&qr16[4]  = *(const float4*)&qq[s][d0 + 4];
        *(float4*)&qr16[8]  = *(const float4*)&qq[s][d0 + 8];
        *(float4*)&qr16[12] = *(const float4*)&qq[s][d0 + 12];
        float p = 0.f;
#pragma unroll
        for (int j = 0; j < 16; ++j) {
            Sacc[j] += kr16[j] * vval;     // S[d][e] += k[d]*v[e]
            p += qr16[j] * Sacc[j];        // num[e] partial
        }
        pnum[dg][e] = p;
        if (t < 64) {
            zreg += kk[s][t];
            float pd = qq[s][t] * zreg;
#pragma unroll
            for (int o = 32; o; o >>= 1) pd += __shfl_down(pd, o);
            if (t == 0) den_sh = pd + 1e-6f;
        }
        __syncthreads();
        if (t < 64) {
            float num = ((pnum[0][t] + pnum[1][t]) + pnum[2][t]) + pnum[3][t];
            a[base + (size_t)s * DD + t] = num / den_sh;
        }
        __syncthreads();
    }
}

// ---------------------------------------------------------------- generic SGEMM
// C[M,N] = A[M,K] @ B[K,N] + bias (+ res) (+ gelu). 64x64 tile, K-tile 16.
// Register-prefetch: next k-tile's global loads issue under current compute.
__global__ __launch_bounds__(256) void gemm_kernel(
    const float* __restrict__ A, const float* __restrict__ B,
    const float* __restrict__ bias, const float* __restrict__ res,
    float* __restrict__ C, int M, int N, int K, int act)
{
    __shared__ float As[16][68];
    __shared__ float Bs[16][68];
    const int t = threadIdx.x;
    const int bn = blockIdx.x, bm = blockIdx.y;
    const int m0 = bm * 64, n0 = bn * 64;
    const int tx = t & 15, ty = t >> 4;
    const int ar = t >> 2, ac = (t & 3) << 2;
    const int br = t >> 4, bc = (t & 15) << 2;
    const float* Ap = A + (size_t)(m0 + ar) * K + ac;
    const float* Bp = B + (size_t)br * N + (n0 + bc);
    float4 av = *(const float4*)(Ap);
    float4 bv = *(const float4*)(Bp);
    float acc[4][4] = {};
    for (int k0 = 0; k0 < K; k0 += 16) {
        As[ac + 0][ar] = av.x; As[ac + 1][ar] = av.y;
        As[ac + 2][ar] = av.z; As[ac + 3][ar] = av.w;
        *(float4*)&Bs[br][bc] = bv;
        __syncthreads();
        if (k0 + 16 < K) {
            av = *(const float4*)(Ap + k0 + 16);
            bv = *(const float4*)(Bp + (size_t)(k0 + 16) * N);
        }
#pragma unroll
        for (int kkk = 0; kkk < 16; ++kkk) {
            float4 a4 = *(const float4*)&As[kkk][ty << 2];
            float4 b4 = *(const float4*)&Bs[kkk][tx << 2];
            float aa[4] = {a4.x, a4.y, a4.z, a4.w};
            float bb4[4] = {b4.x, b4.y, b4.z, b4.w};
#pragma unroll
            for (int i = 0; i < 4; ++i)
#pragma unroll
                for (int jj = 0; jj < 4; ++jj)
                    acc[i][jj] += aa[i] * bb4[jj];
        }
        __syncthreads();
    }
#pragma unroll
    for (int i = 0; i < 4; ++i) {
        int m = m0 + (ty << 2) + i;
        size_t rowoff = (size_t)m * N + n0 + (tx << 2);
        float tmp[4];
#pragma unroll
        for (int jj = 0; jj < 4; ++jj) {
            int n = n0 + (tx << 2) + jj;
            float vv = acc[i][jj] + bias[n];
            if (res) vv += res[rowoff + jj];
            if (act == 1) {
                float x3 = vv * vv * vv;
                vv = vv * (0.5f * (1.0f + tanhf(0.7978845608028654f * (vv + 0.044715f * x3))));
            }
            tmp[jj] = vv;
        }
        float4 o4 = {tmp[0], tmp[1], tmp[2], tmp[3]};
        *(float4*)(C + rowoff) = o4;
    }
}

// ---------------------------------------------------------------- big SGEMM
// 128x128 tile, 8x8 micro-tile (split as 2x 4-wide quads 64 apart to stay
// bank-conflict-free on ds_read_b128). For Wout (N=32000) and W1 (N=2048).
#define PAD128 132
__global__ __launch_bounds__(256) void gemm128_kernel(
    const float* __restrict__ A, const float* __restrict__ B,
    const float* __restrict__ bias, const float* __restrict__ res,
    float* __restrict__ C, int M, int N, int K, int act)
{
    __shared__ float As[16][PAD128];   // transposed A-tile: As[k][m]
    __shared__ float Bs[16][PAD128];
    const int t = threadIdx.x;
    const int bn = blockIdx.x, bm = blockIdx.y;
    const int m0 = bm * 128, n0 = bn * 128;
    const int tx = t & 15, ty = t >> 4;
    const int ar = t >> 2, ac = (t & 3) << 2;     // A stage: 64 rows x 16 cols, 2 halves
    const int br = t >> 5, bc = (t & 31) << 2;    // B stage: 8 rows x 128 cols, 2 halves
    const float* Ap0 = A + (size_t)(m0 + ar) * K + ac;
    const float* Ap1 = A + (size_t)(m0 + 64 + ar) * K + ac;
    const float* Bp0 = B + (size_t)br * N + (n0 + bc);
    const float* Bp1 = B + (size_t)(br + 8) * N + (n0 + bc);
    float4 a0 = *(const float4*)(Ap0);
    float4 a1 = *(const float4*)(Ap1);
    float4 b0 = *(const float4*)(Bp0);
    float4 b1 = *(const float4*)(Bp1);
    float acc[8][8] = {};
    for (int k0 = 0; k0 < K; k0 += 16) {
        As[ac + 0][ar] = a0.x; As[ac + 1][ar] = a0.y;
        As[ac + 2][ar] = a0.z; As[ac + 3][ar] = a0.w;
        As[ac + 0][64 + ar] = a1.x; As[ac + 1][64 + ar] = a1.y;
        As[ac + 2][64 + ar] = a1.z; As[ac + 3][64 + ar] = a1.w;
        *(float4*)&Bs[br][bc] = b0;
        *(float4*)&Bs[br + 8][bc] = b1;
        __syncthreads();
        if (k0 + 16 < K) {
            a0 = *(const float4*)(Ap0 + k0 + 16);
            a1 = *(const float4*)(Ap1 + k0 + 16);
            b0 = *(const float4*)(Bp0 + (size_t)(k0 + 16) * N);
            b1 = *(const float4*)(Bp1 + (size_t)(k0 + 16) * N);
        }
#pragma unroll
        for (int kkk = 0; kkk < 16; ++kkk) {
            float4 aA = *(const float4*)&As[kkk][ty << 2];
            float4 aB = *(const float4*)&As[kkk][64 + (ty << 2)];
            float4 bA = *(const float4*)&Bs[kkk][tx << 2];
            float4 bB = *(const float4*)&Bs[kkk][64 + (tx << 2)];
            float am[8] = {aA.x, aA.y, aA.z, aA.w, aB.x, aB.y, aB.z, aB.w};
            float bn8[8] = {bA.x, bA.y, bA.z, bA.w, bB.x, bB.y, bB.z, bB.w};
#pragma unroll
            for (int i = 0; i < 8; ++i)
#pragma unroll
                for (int jj = 0; jj < 8; ++jj)
                    acc[i][jj] += am[i] * bn8[jj];
        }
        __syncthreads();
    }
#pragma unroll
    for (int i = 0; i < 8; ++i) {
        int m = m0 + ((i >> 2) << 6) + (ty << 2) + (i & 3);
#pragma unroll
        for (int nh = 0; nh < 2; ++nh) {
            int nb = n0 + (nh << 6) + (tx << 2);
            size_t off = (size_t)m * N + nb;
            float tmp[4];
#pragma unroll
            for (int jj = 0; jj < 4; ++jj) {
                float vv2 = acc[i][(nh << 2) + jj] + bias[nb + jj];
                if (res) vv2 += res[off + jj];
                if (act == 1) {
                    float x3 = vv2 * vv2 * vv2;
                    vv2 = vv2 * (0.5f * (1.0f + tanhf(0.7978845608028654f * (vv2 + 0.044715f * x3))));
                }
                tmp[jj] = vv2;
            }
            float4 o4 = {tmp[0], tmp[1], tmp[2], tmp[3]};
            *(float4*)(C + off) = o4;
        }
    }
}

// ---------------------------------------------------------------- cond layernorm
__global__ __launch_bounds__(256) void ln_kernel(
    const float* __restrict__ in, float* __restrict__ out,
    const float* __restrict__ g, const float* __restrict__ b,
    const int* __restrict__ cond)
{
    int row = blockIdx.x;
    int c = cond[row >> 10];
    const float* xr = in + (size_t)row * DD;
    int t = threadIdx.x;
    float v0 = xr[t], v1 = xr[t + 256];
    __shared__ float sm[8];
    int lane = t & 63, w = t >> 6;
    float s1 = v0 + v1;
#pragma unroll
    for (int o = 32; o; o >>= 1) s1 += __shfl_down(s1, o);
    if (lane == 0) sm[w] = s1;
    __syncthreads();
    if (t == 0) sm[0] = sm[0] + sm[1] + sm[2] + sm[3];
    __syncthreads();
    float mu = sm[0] * (1.0f / 512.0f);
    __syncthreads();
    float d0 = v0 - mu, d1 = v1 - mu;
    float s2 = d0 * d0 + d1 * d1;
#pragma unroll
    for (int o = 32; o; o >>= 1) s2 += __shfl_down(s2, o);
    if (lane == 0) sm[w] = s2;
    __syncthreads();
    if (t == 0) sm[0] = sm[0] + sm[1] + sm[2] + sm[3];
    __syncthreads();
    float var = sm[0] * (1.0f / 512.0f);
    float sd = sqrtf(var + 1e-5f);
    const float* gr = g + (size_t)c * DD;
    const float* br = b + (size_t)c * DD;
    out[(size_t)row * DD + t]       = (d0 / sd) * gr[t] + br[t];
    out[(size_t)row * DD + t + 256] = (d1 / sd) * gr[t + 256] + br[t + 256];
}

// ---------------------------------------------------------------- threefry gumbel
__device__ __forceinline__ unsigned rotl32(unsigned x, int r) {
    return (x << r) | (x >> (32 - r));
}

__device__ __forceinline__ float gumbel_noise(unsigned i)
{
    const unsigned k0 = 0u, k1 = 42u, k2 = 0x1BD11BDAu ^ 0u ^ 42u;
    unsigned x0 = 0u;     // counts_hi
    unsigned x1 = i;      // counts_lo
#define TFR(r) { x0 += x1; x1 = rotl32(x1, r); x1 ^= x0; }
    x0 += k0; x1 += k1;
    TFR(13) TFR(15) TFR(26) TFR(6)
    x0 += k1; x1 += k2 + 1u;
    TFR(17) TFR(29) TFR(16) TFR(24)
    x0 += k2; x1 += k0 + 2u;
    TFR(13) TFR(15) TFR(26) TFR(6)
    x0 += k0; x1 += k1 + 3u;
    TFR(17) TFR(29) TFR(16) TFR(24)
    x0 += k1; x1 += k2 + 4u;
    TFR(13) TFR(15) TFR(26) TFR(6)
    x0 += k2; x1 += k0 + 5u;
#undef TFR
    unsigned bits = x0 ^ x1;
    float u = __uint_as_float((bits >> 9) | 0x3f800000u) - 1.0f;
    float uu = u > 0.f ? u : 1.175494350822288e-38f;   // max(tiny, u) — matches jax uniform
    return -logf(-logf(uu));
}

__global__ __launch_bounds__(256) void gumbel_argmax_kernel(
    const float* __restrict__ logits, float* __restrict__ out1)
{
    int row = blockIdx.x;
    unsigned base = (unsigned)row * VV;
    int t = threadIdx.x;
    float best = -3.4e38f;
    int bi = VV;
    for (int v = t; v < VV; v += 256) {
        float val = logits[base + v] + gumbel_noise(base + v);
        if (val > best) { best = val; bi = v; }   // keeps first occurrence
    }
    __shared__ float bv[256];
    __shared__ int bix[256];
    bv[t] = best; bix[t] = bi;
    __syncthreads();
    for (int off = 128; off; off >>= 1) {
        if (t < off) {
            float ov = bv[t + off]; int oi = bix[t + off];
            if (ov > bv[t] || (ov == bv[t] && oi < bix[t])) { bv[t] = ov; bix[t] = oi; }
        }
        __syncthreads();
    }
    int amax = bix[0];
    for (int v = t; v < VV; v += 256)
        out1[base + v] = (v == amax) ? 1.0f : 0.0f;
}

// ---------------------------------------------------------------- launch
extern "C" void kernel_launch(void* const* d_in, const int* in_sizes, int n_in,
                              void* d_out, int out_size, void* d_ws, size_t ws_size,
                              hipStream_t stream)
{
    const int*   ids   = (const int*)  d_in[0];
    const int*   cond  = (const int*)  d_in[1];
    const float* mask  = (const float*)d_in[2];
    // d_in[3] = inverse_temperature (==1, cancels in argmax) — unused
    const float* emb   = (const float*)d_in[4];
    const float* pos   = (const float*)d_in[5];
    const float* Wq    = (const float*)d_in[6];
    const float* bq    = (const float*)d_in[7];
    const float* Wk    = (const float*)d_in[8];
    const float* bk    = (const float*)d_in[9];
    const float* Wv    = (const float*)d_in[10];
    const float* bv    = (const float*)d_in[11];
    const float* Wo    = (const float*)d_in[12];
    const float* bo    = (const float*)d_in[13];
    const float* W1    = (const float*)d_in[14];
    const float* b1    = (const float*)d_in[15];
    const float* W2    = (const float*)d_in[16];
    const float* b2    = (const float*)d_in[17];
    const float* cn1g  = (const float*)d_in[18];
    const float* cn1b  = (const float*)d_in[19];
    const float* cn2g  = (const float*)d_in[20];
    const float* cn2b  = (const float*)d_in[21];
    const float* ng    = (const float*)d_in[22];
    const float* nb    = (const float*)d_in[23];
    const float* Wout  = (const float*)d_in[24];
    const float* bout  = (const float*)d_in[25];

    float* out0 = (float*)d_out;
    float* out1 = out0 + (size_t)NTOT;

    const size_t NX = (size_t)ROWS * DD;     // 1,048,576
    float* ws   = (float*)d_ws;
    float* x    = ws;
    float* xr   = x + NX;
    float* qb   = xr + NX;
    float* kb   = qb + NX;
    float* vb2  = kb + NX;
    float* ab   = vb2 + NX;
    float* h1   = ab + NX;                   // ROWS*FF = 4,194,304
    float* ctab = h1 + (size_t)ROWS * FF;
    float* stab = ctab + SS * 32;

    // chunk-attn scratch aliases h1 (free until the W1 gemm runs):
    // states: B*H*NCHUNK*64*64 = 1,048,576 floats; zsums: B*H*NCHUNK*64 = 16,384
    float* stbuf = h1;
    float* zbuf  = h1 + (size_t)BB * HH * NCHUNK * 4096;

    embed_kernel<<<(ROWS * DD) / 256, 256, 0, stream>>>(ids, emb, pos, x);
    rope_table_kernel<<<(SS * 32) / 256, 256, 0, stream>>>(ctab, stab);

    for (int l = 0; l < LL; ++l) {
        const float* wq = Wq + (size_t)l * DD * DD;
        const float* wk = Wk + (size_t)l * DD * DD;
        const float* wv = Wv + (size_t)l * DD * DD;
        const float* wo = Wo + (size_t)l * DD * DD;
        const float* w1 = W1 + (size_t)l * DD * FF;
        const float* w2 = W2 + (size_t)l * FF * DD;

        dim3 g512(DD / 64, ROWS / 64);
        gemm_kernel<<<g512, 256, 0, stream>>>(x, wq, bq + l * DD, nullptr, qb, ROWS, DD, DD, 0);
        gemm_kernel<<<g512, 256, 0, stream>>>(x, wk, bk + l * DD, nullptr, kb, ROWS, DD, DD, 0);
        gemm_kernel<<<g512, 256, 0, stream>>>(x, wv, bv + l * DD, nullptr, vb2, ROWS, DD, DD, 0);

        rope_feat_kernel<<<(ROWS * HH * 32) / 256, 256, 0, stream>>>(qb, kb, ctab, stab, mask);

        chunk_state_kernel<<<BB * HH * NCHUNK, 256, 0, stream>>>(kb, vb2, stbuf, zbuf);
        chunk_prefix_kernel<<<BB * HH, 256, 0, stream>>>(stbuf, zbuf);
        chunk_scan_kernel<<<BB * HH * NCHUNK, 256, 0, stream>>>(qb, kb, vb2, ab, stbuf, zbuf);

        gemm_kernel<<<g512, 256, 0, stream>>>(ab, wo, bo + l * DD, x, xr, ROWS, DD, DD, 0);
        ln_kernel<<<ROWS, 256, 0, stream>>>(xr, x, cn1g + (size_t)l * 4 * DD, cn1b + (size_t)l * 4 * DD, cond);

        dim3 g128f(FF / 128, ROWS / 128);
        gemm128_kernel<<<g128f, 256, 0, stream>>>(x, w1, b1 + l * FF, nullptr, h1, ROWS, FF, DD, 1);
        gemm_kernel<<<dim3(DD / 64, ROWS / 64), 256, 0, stream>>>(h1, w2, b2 + l * DD, x, xr, ROWS, DD, FF, 0);
        ln_kernel<<<ROWS, 256, 0, stream>>>(xr, x, cn2g + (size_t)l * 4 * DD, cn2b + (size_t)l * 4 * DD, cond);
    }

    ln_kernel<<<ROWS, 256, 0, stream>>>(x, xr, ng, nb, cond);

    dim3 gV128(VV / 128, ROWS / 128);
    gemm128_kernel<<<gV128, 256, 0, stream>>>(xr, Wout, bout, nullptr, out0, ROWS, VV, DD, 0);

    gumbel_argmax_kernel<<<ROWS, 256, 0, stream>>>(out0, out1);
}